// Round 11
// baseline (643.388 us; speedup 1.0000x reference)
//
#include <hip/hip_runtime.h>
#include <stdint.h>

typedef unsigned short u16;
typedef __attribute__((ext_vector_type(8))) __bf16 bf16x8;
typedef __attribute__((ext_vector_type(8))) unsigned short u16x8;
typedef __attribute__((ext_vector_type(4))) float f32x4;

#define NREL 7
#define DIM  512
#define DEDGE 59
#define KC   420     // NREL*59 + NREL (weight-sum columns)
#define KCP  448     // padded to multiple of 32
#define KU   3584    // NREL*512 (node-path U region)
#define KTOT 4544    // KU + 512 (self, served from NF) + 448 (edge-G)

__device__ __forceinline__ float bf2f(u16 u) {
  union { unsigned u; float f; } c; c.u = ((unsigned)u) << 16; return c.f;
}
__device__ __forceinline__ u16 f2bf(float f) {
  union { float f; unsigned u; } c; c.f = f;
  unsigned r = ((c.u >> 16) & 1u) + 0x7FFFu;
  return (u16)((c.u + r) >> 16);
}

__device__ __forceinline__ void gload16(const void* g, void* l) {
  __builtin_amdgcn_global_load_lds(
      (__attribute__((address_space(1))) void*)g,
      (__attribute__((address_space(3))) void*)l, 16, 0, 0);
}

// ---- convert node_feat fp32 -> bf16 NF table [N,512] ----
__global__ void convA(const float* __restrict__ in, u16* __restrict__ out, int total4) {
  int i = blockIdx.x * 256 + threadIdx.x;
  if (i >= total4) return;
  float4 v = ((const float4*)in)[i];
  ushort4 r;
  r.x = f2bf(v.x); r.y = f2bf(v.y); r.z = f2bf(v.z); r.w = f2bf(v.w);
  ((ushort4*)out)[i] = r;
}

// ---- Bfull[o][k] bf16, [512][KTOT]: k<3584 -> W_lin[o][k]; 3584..4095 -> W_self[o][k-3584] ----
__global__ void buildBW(const float* __restrict__ W_lin, const float* __restrict__ W_self,
                        u16* __restrict__ Bfull, int total4) {
  int gid = blockIdx.x * 256 + threadIdx.x;
  if (gid >= total4) return;
  int idx = gid * 4;
  int o = idx >> 12;          // / 4096
  int k = idx & 4095;
  const float* src = (k < KU) ? (W_lin + (size_t)o * KU + k)
                              : (W_self + (size_t)o * DIM + (k - KU));
  float4 v = *(const float4*)src;
  ushort4 rr;
  rr.x = f2bf(v.x); rr.y = f2bf(v.y); rr.z = f2bf(v.z); rr.w = f2bf(v.w);
  *(ushort4*)(Bfull + (size_t)o * KTOT + k) = rr;
}

// ---- Bfull cols [4096, 4544): c=r*59+de -> sum_d W_edge[d,de]*W_lin[o,r*512+d];
//      c=413+r -> sum_d b_edge[d]*W_lin[o,r*512+d]; c>=420 -> 0 ----
__global__ __launch_bounds__(512) void buildCx(const float* __restrict__ W_edge,
                                               const float* __restrict__ b_edge,
                                               const float* __restrict__ W_lin,
                                               u16* __restrict__ Bfull) {
  int c = blockIdx.x;          // 0..447
  int o = threadIdx.x;         // 0..511
  u16* dst = Bfull + (size_t)o * KTOT + KU + DIM;  // col base 4096
  if (c >= KC) { dst[c] = 0; return; }
  __shared__ float col[DIM];
  int r;
  if (c < NREL * DEDGE) {
    r = c / DEDGE;
    int de = c - r * DEDGE;
    col[o] = W_edge[(size_t)o * DEDGE + de];
  } else {
    r = c - NREL * DEDGE;
    col[o] = b_edge[o];
  }
  __syncthreads();
  const float* wrow = W_lin + (size_t)o * KU + (size_t)r * DIM;
  float acc = 0.f;
#pragma unroll 8
  for (int d = 0; d < DIM; ++d) acc += col[d] * wrow[d];
  dst[c] = f2bf(acc);
}

// ---- two-level CSR keyed by (node_out, relation) ----
__global__ void countK2(const int* __restrict__ node_out, const int* __restrict__ relation,
                        int* __restrict__ counts2, int E) {
  int e = blockIdx.x * 256 + threadIdx.x;
  if (e < E) atomicAdd(&counts2[node_out[e] * 8 + relation[e]], 1);
}

// segment bases via atomic allocation — CSR segment ORDER is irrelevant (only
// disjointness matters), so no prefix scan needed.
__global__ void baseK(const int* __restrict__ counts2, int* __restrict__ offs2,
                      int* __restrict__ cursor2, int* __restrict__ totalCtr, int N) {
  int n = blockIdx.x * 256 + threadIdx.x;
  if (n >= N) return;
  int cnt[NREL];
  int s = 0;
#pragma unroll
  for (int r = 0; r < NREL; ++r) { cnt[r] = counts2[n * 8 + r]; s += cnt[r]; }
  int base = atomicAdd(totalCtr, s);
#pragma unroll
  for (int r = 0; r < NREL; ++r) {
    offs2[n * 8 + r] = base;
    cursor2[n * 8 + r] = base;
    base += cnt[r];
  }
  offs2[n * 8 + 7] = base;
}

// one 16B scattered store per edge: quad = (src, w_bits, e, 0)
__global__ void fillK2(const int* __restrict__ node_in, const int* __restrict__ node_out,
                       const int* __restrict__ relation, const float* __restrict__ ew,
                       int* __restrict__ cursor2, uint4* __restrict__ quads, int E) {
  int e = blockIdx.x * 256 + threadIdx.x;
  if (e >= E) return;
  int p = atomicAdd(&cursor2[node_out[e] * 8 + relation[e]], 1);
  quads[p] = make_uint4((unsigned)node_in[e], __float_as_uint(ew[e]), (unsigned)e, 0u);
}

// ---- pass-partitioned node-path aggregation: U[n][r*512+d] = sum w_e * NF[src_e][d].
//      Grid = 8 passes x N nodes (pass = bid/N varies SLOWEST so concurrently-resident
//      blocks share one pass's NF column slice: N x 128B = 2.56 MB < 4 MB/XCD L2).
//      One wave per (node,pass): 8 lane-groups x 8 lanes process 8 edges concurrently;
//      their quad reads coalesce to one 128B line-pair; each group reads a contiguous
//      128B NF sub-row. Cross-group reduce = 3 shfl_xor. ----
__global__ __launch_bounds__(64) void aggP(const u16* __restrict__ NF,
                                           const uint4* __restrict__ quads,
                                           const int* __restrict__ offs2,
                                           u16* __restrict__ U, int N) {
  int bid = blockIdx.x;
  int dp = bid / N;                 // 0..7, slow-varying
  int n  = bid - dp * N;
  int l = threadIdx.x;
  int grp = l >> 3, gl = l & 7;     // lane-group, lane-in-group
  int c0 = dp * 64 + gl * 8;        // this lane's 8 columns
  int base = n * 8;
  u16* urow = U + (size_t)n * KU;
  for (int r = 0; r < NREL; ++r) {
    int p0 = offs2[base + r], p1 = offs2[base + r + 1];
    float a[8];
#pragma unroll
    for (int j = 0; j < 8; ++j) a[j] = 0.f;
    for (int p = p0 + grp; p < p1; p += 8) {
      uint4 q = quads[p];
      float w = __uint_as_float(q.y);
      int src = (int)q.x;
      u16x8 hv = *(const u16x8*)(NF + (size_t)src * DIM + c0);
#pragma unroll
      for (int j = 0; j < 8; ++j) a[j] += w * bf2f(hv[j]);
    }
#pragma unroll
    for (int j = 0; j < 8; ++j) {
      a[j] += __shfl_xor(a[j], 8);
      a[j] += __shfl_xor(a[j], 16);
      a[j] += __shfl_xor(a[j], 32);
    }
    if (grp == 0) {
      u16x8 st;
#pragma unroll
      for (int j = 0; j < 8; ++j) st[j] = f2bf(a[j]);
      *(u16x8*)(urow + (size_t)r * DIM + c0) = st;  // lanes 0-7: contiguous 128B
    }
  }
}

// ---- edge-G aggregation (rel-segmented, atomic-free): G[n][0..448) ----
//      ef reads are compulsory HBM (151 MB table, no reuse); 20K waves give the MLP.
__global__ __launch_bounds__(64) void gatherG2(const float* __restrict__ ef,
                                               const uint4* __restrict__ quads,
                                               const int* __restrict__ offs2,
                                               u16* __restrict__ G) {
  int n = blockIdx.x;
  int lane = threadIdx.x;
  u16* grow = G + (size_t)n * KCP;
  int base = n * 8;
  for (int r = 0; r < NREL; ++r) {
    int p0 = offs2[base + r], p1 = offs2[base + r + 1];
    float acc = 0.f;
    for (int p = p0; p < p1; ++p) {
      uint4 q = quads[p];
      int e = __builtin_amdgcn_readfirstlane((int)q.z);
      float w = __uint_as_float(__builtin_amdgcn_readfirstlane(q.y));
      float v = (lane < DEDGE) ? ef[(size_t)e * DEDGE + lane] : 1.0f;
      acc += w * v;
    }
    if (lane < DEDGE) grow[r * DEDGE + lane] = f2bf(acc);
    else if (lane == DEDGE) grow[NREL * DEDGE + r] = f2bf(acc);
  }
  if (lane >= 60) {
    for (int c = KC + (lane - 60); c < KCP; c += 4) grow[c] = 0;
  }
}

// ---- fused MFMA GEMM: out[M,512] = relu([U | NF | G] @ Bfull^T + b_lin + b_self)
//      A region-split: kt<112 -> U[M,3584]; 112..127 -> NF[M,512]; >=128 -> G[M,448].
//      R6 proven-best structure: T2 XOR bank-swizzle (conflicts=0), 3-buffer
//      counted-vmcnt pipeline, XCD panel-grouping swizzle, 128x128 block. ----
__global__ __launch_bounds__(256) void gemm_br(const u16* __restrict__ U,
                                               const u16* __restrict__ NF,
                                               const u16* __restrict__ G,
                                               const u16* __restrict__ Bt,
                                               const float* __restrict__ b_lin,
                                               const float* __restrict__ b_self,
                                               float* __restrict__ Cout, int M) {
  __shared__ __align__(16) u16 sA[3][128 * 32];
  __shared__ __align__(16) u16 sB[3][128 * 32];
  const int tid = threadIdx.x;
  const int w = tid >> 6, l = tid & 63;
  const int lr = l & 15, kg = l >> 4;
  const int sl = kg ^ ((lr >> 1) & 3);   // swizzled 16B-slot to read (lane-constant)

  const int id = blockIdx.x;
  const int npan = gridDim.x >> 2;
  const int nfull = (npan >> 3) << 3;
  int p, c;
  if (id < nfull * 4) {
    int g = id >> 5, r = id & 31;
    p = g * 8 + (r & 7);
    c = r >> 3;
  } else {
    int t = id - nfull * 4;
    p = nfull + (t >> 2);
    c = t & 3;
  }
  const int m0 = p * 128, n0 = c * 128;
  const int wr = w >> 1, wc = w & 1;
  f32x4 acc[4][4];
  const f32x4 z4 = {0.f, 0.f, 0.f, 0.f};
#pragma unroll
  for (int i = 0; i < 4; ++i)
#pragma unroll
    for (int j = 0; j < 4; ++j) acc[i][j] = z4;

  const int ktiles = KTOT / 32;   // 142

  auto stage = [&](int kt, int b) {
    const u16* Ab; int astr, ac0;
    if (kt < 112)      { Ab = U;  astr = KU;  ac0 = kt * 32; }
    else if (kt < 128) { Ab = NF; astr = DIM; ac0 = kt * 32 - KU; }
    else               { Ab = G;  astr = KCP; ac0 = kt * 32 - (KU + DIM); }
    const int k0 = kt * 32;
#pragma unroll
    for (int t = 0; t < 2; ++t) {
      int idx = w * 128 + t * 64 + l;     // 16B granule id within A tile (linear dest)
      int row = idx >> 2, kp = idx & 3;
      int s = kp ^ ((row >> 1) & 3);
      int gm = m0 + row; gm = gm < M ? gm : M - 1;
      gload16(Ab + (size_t)gm * astr + ac0 + s * 8,
              (char*)sA[b] + (size_t)idx * 16);
    }
#pragma unroll
    for (int t = 0; t < 2; ++t) {
      int idx = w * 128 + t * 64 + l;
      int row = idx >> 2, kp = idx & 3;
      int s = kp ^ ((row >> 1) & 3);
      gload16(Bt + (size_t)(n0 + row) * KTOT + k0 + s * 8,
              (char*)sB[b] + (size_t)idx * 16);
    }
  };

  stage(0, 0);
  stage(1, 1);
  asm volatile("s_waitcnt vmcnt(4)" ::: "memory");
  __builtin_amdgcn_s_barrier();
  __builtin_amdgcn_sched_barrier(0);

  for (int kt = 0; kt < ktiles; ++kt) {
    const int cur = kt % 3;
    if (kt + 2 < ktiles) stage(kt + 2, (kt + 2) % 3);
    bf16x8 af[4], bfr[4];
#pragma unroll
    for (int i = 0; i < 4; ++i)
      af[i] = *(const bf16x8*)(sA[cur] + (size_t)(wr * 64 + i * 16 + lr) * 32 + sl * 8);
#pragma unroll
    for (int j = 0; j < 4; ++j)
      bfr[j] = *(const bf16x8*)(sB[cur] + (size_t)(wc * 64 + j * 16 + lr) * 32 + sl * 8);
#pragma unroll
    for (int i = 0; i < 4; ++i)
#pragma unroll
      for (int j = 0; j < 4; ++j)
        acc[i][j] = __builtin_amdgcn_mfma_f32_16x16x32_bf16(af[i], bfr[j], acc[i][j], 0, 0, 0);
    if (kt + 2 < ktiles) {
      asm volatile("s_waitcnt vmcnt(4)" ::: "memory");
    } else {
      asm volatile("s_waitcnt vmcnt(0)" ::: "memory");
    }
    __builtin_amdgcn_s_barrier();
    __builtin_amdgcn_sched_barrier(0);
  }
#pragma unroll
  for (int i = 0; i < 4; ++i) {
#pragma unroll
    for (int j = 0; j < 4; ++j) {
      int gj = n0 + wc * 64 + j * 16 + lr;
      float bias = b_lin[gj] + b_self[gj];
#pragma unroll
      for (int v = 0; v < 4; ++v) {
        int gm = m0 + wr * 64 + i * 16 + kg * 4 + v;
        if (gm < M)
          ((float*)Cout)[(size_t)gm * DIM + gj] = fmaxf(acc[i][j][v] + bias, 0.f);
      }
    }
  }
}

extern "C" void kernel_launch(void* const* d_in, const int* in_sizes, int n_in,
                              void* d_out, int out_size, void* d_ws, size_t ws_size,
                              hipStream_t stream) {
  const float* node_feat = (const float*)d_in[0];
  const float* edge_weight = (const float*)d_in[1];
  const float* edge_feat = (const float*)d_in[2];
  const float* W_lin = (const float*)d_in[3];
  const float* b_lin = (const float*)d_in[4];
  const float* W_self = (const float*)d_in[5];
  const float* b_self = (const float*)d_in[6];
  const float* W_edge = (const float*)d_in[7];
  const float* b_edge = (const float*)d_in[8];
  const int* node_in = (const int*)d_in[9];
  const int* node_out = (const int*)d_in[10];
  const int* relation = (const int*)d_in[11];
  float* out = (float*)d_out;

  const int N = in_sizes[0] / DIM;
  const int E = in_sizes[1];

  char* ws = (char*)d_ws;
  size_t off = 0;
  auto take = [&](size_t b) {
    char* p = ws + off;
    off += (b + 255) & ~(size_t)255;
    return p;
  };
  u16* NF       = (u16*)take((size_t)N * DIM * 2);
  u16* Bfull    = (u16*)take((size_t)DIM * KTOT * 2);
  u16* U        = (u16*)take((size_t)N * KU * 2);
  u16* G        = (u16*)take((size_t)N * KCP * 2);
  int* counts2  = (int*)take((size_t)N * 8 * 4);
  int* offs2    = (int*)take((size_t)N * 8 * 4);
  int* cursor2  = (int*)take((size_t)N * 8 * 4);
  int* totalCtr = (int*)take(256);
  uint4* quads  = (uint4*)take((size_t)E * 16);
  if (off > ws_size) return;  // workspace too small — fail visibly via absmax

  hipMemsetAsync(counts2, 0, (size_t)N * 8 * 4, stream);
  hipMemsetAsync(totalCtr, 0, 256, stream);

  {
    int total4 = N * DIM / 4;
    convA<<<(total4 + 255) / 256, 256, 0, stream>>>(node_feat, NF, total4);
  }
  {
    int total4 = DIM * 4096 / 4;
    buildBW<<<(total4 + 255) / 256, 256, 0, stream>>>(W_lin, W_self, Bfull, total4);
  }
  buildCx<<<KCP, 512, 0, stream>>>(W_edge, b_edge, W_lin, Bfull);

  countK2<<<(E + 255) / 256, 256, 0, stream>>>(node_out, relation, counts2, E);
  baseK<<<(N + 255) / 256, 256, 0, stream>>>(counts2, offs2, cursor2, totalCtr, N);
  fillK2<<<(E + 255) / 256, 256, 0, stream>>>(node_in, node_out, relation, edge_weight,
                                              cursor2, quads, E);

  // edge-G (HBM-compulsory ef gather) — independent of the NF gather
  gatherG2<<<N, 64, 0, stream>>>(edge_feat, quads, offs2, G);
  // node-path U: pass-partitioned L2-resident NF gather
  aggP<<<8 * N, 64, 0, stream>>>(NF, quads, offs2, U, N);

  // single fused GEMM + bias + relu (A = [U | NF | G] region-split; 1-D swizzled grid)
  {
    int npan = (N + 127) / 128;
    gemm_br<<<npan * 4, 256, 0, stream>>>(U, NF, G, Bfull, b_lin, b_self, out, N);
  }
}

// Round 12
// 604.928 us; speedup vs baseline: 1.0636x; 1.0636x over previous
//
#include <hip/hip_runtime.h>
#include <stdint.h>

typedef unsigned short u16;
typedef __attribute__((ext_vector_type(8))) __bf16 bf16x8;
typedef __attribute__((ext_vector_type(8))) unsigned short u16x8;
typedef __attribute__((ext_vector_type(4))) float f32x4;
typedef __attribute__((ext_vector_type(4))) unsigned int u32x4;

#define NREL 7
#define DIM  512
#define DEDGE 59
#define KC   420     // NREL*59 + NREL (weight-sum columns)
#define KCP  448     // padded to multiple of 32
#define KU   3584    // NREL*512 (node-path U region)
#define KTOT 4544    // KU + 512 (self, served from NF) + 448 (edge-G)

__device__ __forceinline__ float bf2f(u16 u) {
  union { unsigned u; float f; } c; c.u = ((unsigned)u) << 16; return c.f;
}
__device__ __forceinline__ u16 f2bf(float f) {
  union { float f; unsigned u; } c; c.f = f;
  unsigned r = ((c.u >> 16) & 1u) + 0x7FFFu;
  return (u16)((c.u + r) >> 16);
}

__device__ __forceinline__ void gload16(const void* g, void* l) {
  __builtin_amdgcn_global_load_lds(
      (__attribute__((address_space(1))) void*)g,
      (__attribute__((address_space(3))) void*)l, 16, 0, 0);
}

// ---- convert node_feat fp32 -> bf16 NF table [N,512] ----
__global__ void convA(const float* __restrict__ in, u16* __restrict__ out, int total4) {
  int i = blockIdx.x * 256 + threadIdx.x;
  if (i >= total4) return;
  float4 v = ((const float4*)in)[i];
  ushort4 r;
  r.x = f2bf(v.x); r.y = f2bf(v.y); r.z = f2bf(v.z); r.w = f2bf(v.w);
  ((ushort4*)out)[i] = r;
}

// ---- Bfull[o][k] bf16, [512][KTOT]: k<3584 -> W_lin[o][k]; 3584..4095 -> W_self[o][k-3584] ----
__global__ void buildBW(const float* __restrict__ W_lin, const float* __restrict__ W_self,
                        u16* __restrict__ Bfull, int total4) {
  int gid = blockIdx.x * 256 + threadIdx.x;
  if (gid >= total4) return;
  int idx = gid * 4;
  int o = idx >> 12;          // / 4096
  int k = idx & 4095;
  const float* src = (k < KU) ? (W_lin + (size_t)o * KU + k)
                              : (W_self + (size_t)o * DIM + (k - KU));
  float4 v = *(const float4*)src;
  ushort4 rr;
  rr.x = f2bf(v.x); rr.y = f2bf(v.y); rr.z = f2bf(v.z); rr.w = f2bf(v.w);
  *(ushort4*)(Bfull + (size_t)o * KTOT + k) = rr;
}

// ---- Bfull cols [4096, 4544): c=r*59+de -> sum_d W_edge[d,de]*W_lin[o,r*512+d];
//      c=413+r -> sum_d b_edge[d]*W_lin[o,r*512+d]; c>=420 -> 0 ----
__global__ __launch_bounds__(512) void buildCx(const float* __restrict__ W_edge,
                                               const float* __restrict__ b_edge,
                                               const float* __restrict__ W_lin,
                                               u16* __restrict__ Bfull) {
  int c = blockIdx.x;          // 0..447
  int o = threadIdx.x;         // 0..511
  u16* dst = Bfull + (size_t)o * KTOT + KU + DIM;  // col base 4096
  if (c >= KC) { dst[c] = 0; return; }
  __shared__ float col[DIM];
  int r;
  if (c < NREL * DEDGE) {
    r = c / DEDGE;
    int de = c - r * DEDGE;
    col[o] = W_edge[(size_t)o * DEDGE + de];
  } else {
    r = c - NREL * DEDGE;
    col[o] = b_edge[o];
  }
  __syncthreads();
  const float4* wv = (const float4*)(W_lin + (size_t)o * KU + (size_t)r * DIM);
  float acc = 0.f;
#pragma unroll 4
  for (int d4 = 0; d4 < DIM / 4; ++d4) {
    float4 wq = wv[d4];
    acc += col[d4 * 4 + 0] * wq.x + col[d4 * 4 + 1] * wq.y
         + col[d4 * 4 + 2] * wq.z + col[d4 * 4 + 3] * wq.w;
  }
  dst[c] = f2bf(acc);
}

// ---- two-level CSR keyed by (node_out, relation) ----
__global__ void countK2(const int* __restrict__ node_out, const int* __restrict__ relation,
                        int* __restrict__ counts2, int E) {
  int e = blockIdx.x * 256 + threadIdx.x;
  if (e < E) atomicAdd(&counts2[node_out[e] * 8 + relation[e]], 1);
}

// segment bases via atomic allocation — CSR segment ORDER is irrelevant (only
// disjointness matters), so no prefix scan needed.
__global__ void baseK(const int* __restrict__ counts2, int* __restrict__ offs2,
                      int* __restrict__ cursor2, int* __restrict__ totalCtr, int N) {
  int n = blockIdx.x * 256 + threadIdx.x;
  if (n >= N) return;
  int cnt[NREL];
  int s = 0;
#pragma unroll
  for (int r = 0; r < NREL; ++r) { cnt[r] = counts2[n * 8 + r]; s += cnt[r]; }
  int base = atomicAdd(totalCtr, s);
#pragma unroll
  for (int r = 0; r < NREL; ++r) {
    offs2[n * 8 + r] = base;
    cursor2[n * 8 + r] = base;
    base += cnt[r];
  }
  offs2[n * 8 + 7] = base;
}

// one 16B scattered store per edge: quad = (src, w_bits, e, 0)
__global__ void fillK2(const int* __restrict__ node_in, const int* __restrict__ node_out,
                       const int* __restrict__ relation, const float* __restrict__ ew,
                       int* __restrict__ cursor2, uint4* __restrict__ quads, int E) {
  int e = blockIdx.x * 256 + threadIdx.x;
  if (e >= E) return;
  int p = atomicAdd(&cursor2[node_out[e] * 8 + relation[e]], 1);
  quads[p] = make_uint4((unsigned)node_in[e], __float_as_uint(ew[e]), (unsigned)e, 0u);
}

// ---- pass-partitioned node-path aggregation, GROUP-PER-NODE (no cross-lane reduce):
//      U[n][r*512+d] = sum w_e * NF[src_e][d].
//      Grid = 8 passes x ceil(N/32) blocks (pass varies SLOWEST: co-resident blocks
//      share one pass's NF column panel = N x 128B = 2.56 MB < 4 MB/XCD L2).
//      Block = 4 waves; wave = 8 groups of 8 lanes; group owns ONE node and walks its
//      (r)-segments serially; lane gl owns 8 cols -> accumulators stay in-register,
//      store = contiguous 128B per group. Quads prefetched 1 ahead (branchless clamp)
//      and loaded non-temporally (protect the NF panel); U stores non-temporal. ----
__global__ __launch_bounds__(256) void aggP(const u16* __restrict__ NF,
                                            const uint4* __restrict__ quads,
                                            const int* __restrict__ offs2,
                                            u16* __restrict__ U, int N, int nb) {
  int bid = blockIdx.x;
  int dp = bid / nb;                    // 0..7, slow-varying pass
  int b  = bid - dp * nb;
  int wv = threadIdx.x >> 6, l = threadIdx.x & 63;
  int grp = l >> 3, gl = l & 7;         // group (node slot), lane-in-group
  int n = b * 32 + wv * 8 + grp;
  bool valid = n < N;
  int nn = valid ? n : N - 1;
  int c0 = dp * 64 + gl * 8;            // this lane's 8 feature cols
  // preload this node's offs2 row (8 ints, 32B) into registers
  const u32x4* orow = (const u32x4*)(offs2 + nn * 8);
  u32x4 oa = orow[0], ob = orow[1];
  int offr[8] = {(int)oa.x, (int)oa.y, (int)oa.z, (int)oa.w,
                 (int)ob.x, (int)ob.y, (int)ob.z, (int)ob.w};
  u16* ubase = U + (size_t)nn * KU + c0;
#pragma unroll
  for (int r = 0; r < NREL; ++r) {
    int p0 = offr[r], p1 = offr[r + 1];
    float a[8];
#pragma unroll
    for (int j = 0; j < 8; ++j) a[j] = 0.f;
    if (p0 < p1) {
      u32x4 q = __builtin_nontemporal_load((const u32x4*)(quads + p0));
      for (int p = p0; p < p1; ++p) {
        int pn = p + 1 < p1 ? p + 1 : p1 - 1;   // branchless clamp-prefetch
        u32x4 qn = __builtin_nontemporal_load((const u32x4*)(quads + pn));
        float w = __uint_as_float(q.y);
        int src = (int)q.x;
        u16x8 hv = *(const u16x8*)(NF + (size_t)src * DIM + c0);
#pragma unroll
        for (int j = 0; j < 8; ++j) a[j] += w * bf2f(hv[j]);
        q = qn;
      }
    }
    u16x8 st;
#pragma unroll
    for (int j = 0; j < 8; ++j) st[j] = f2bf(a[j]);
    if (valid)
      __builtin_nontemporal_store(st, (u16x8*)(ubase + (size_t)r * DIM));
  }
}

// ---- edge-G aggregation (rel-segmented, atomic-free): G[n][0..448) ----
//      ef reads are compulsory HBM (151 MB table, no reuse); 20K waves give the MLP.
__global__ __launch_bounds__(64) void gatherG2(const float* __restrict__ ef,
                                               const uint4* __restrict__ quads,
                                               const int* __restrict__ offs2,
                                               u16* __restrict__ G) {
  int n = blockIdx.x;
  int lane = threadIdx.x;
  u16* grow = G + (size_t)n * KCP;
  int base = n * 8;
  for (int r = 0; r < NREL; ++r) {
    int p0 = offs2[base + r], p1 = offs2[base + r + 1];
    float acc = 0.f;
    for (int p = p0; p < p1; ++p) {
      uint4 q = quads[p];
      int e = __builtin_amdgcn_readfirstlane((int)q.z);
      float w = __uint_as_float(__builtin_amdgcn_readfirstlane(q.y));
      float v = (lane < DEDGE) ? ef[(size_t)e * DEDGE + lane] : 1.0f;
      acc += w * v;
    }
    if (lane < DEDGE) grow[r * DEDGE + lane] = f2bf(acc);
    else if (lane == DEDGE) grow[NREL * DEDGE + r] = f2bf(acc);
  }
  if (lane >= 60) {
    for (int c = KC + (lane - 60); c < KCP; c += 4) grow[c] = 0;
  }
}

// ---- fused MFMA GEMM: out[M,512] = relu([U | NF | G] @ Bfull^T + b_lin + b_self)
//      A region-split: kt<112 -> U[M,3584]; 112..127 -> NF[M,512]; >=128 -> G[M,448].
//      R6 proven-best structure: T2 XOR bank-swizzle (conflicts=0), 3-buffer
//      counted-vmcnt pipeline, XCD panel-grouping swizzle, 128x128 block. ----
__global__ __launch_bounds__(256) void gemm_br(const u16* __restrict__ U,
                                               const u16* __restrict__ NF,
                                               const u16* __restrict__ G,
                                               const u16* __restrict__ Bt,
                                               const float* __restrict__ b_lin,
                                               const float* __restrict__ b_self,
                                               float* __restrict__ Cout, int M) {
  __shared__ __align__(16) u16 sA[3][128 * 32];
  __shared__ __align__(16) u16 sB[3][128 * 32];
  const int tid = threadIdx.x;
  const int w = tid >> 6, l = tid & 63;
  const int lr = l & 15, kg = l >> 4;
  const int sl = kg ^ ((lr >> 1) & 3);   // swizzled 16B-slot to read (lane-constant)

  const int id = blockIdx.x;
  const int npan = gridDim.x >> 2;
  const int nfull = (npan >> 3) << 3;
  int p, c;
  if (id < nfull * 4) {
    int g = id >> 5, r = id & 31;
    p = g * 8 + (r & 7);
    c = r >> 3;
  } else {
    int t = id - nfull * 4;
    p = nfull + (t >> 2);
    c = t & 3;
  }
  const int m0 = p * 128, n0 = c * 128;
  const int wr = w >> 1, wc = w & 1;
  f32x4 acc[4][4];
  const f32x4 z4 = {0.f, 0.f, 0.f, 0.f};
#pragma unroll
  for (int i = 0; i < 4; ++i)
#pragma unroll
    for (int j = 0; j < 4; ++j) acc[i][j] = z4;

  const int ktiles = KTOT / 32;   // 142

  auto stage = [&](int kt, int b) {
    const u16* Ab; int astr, ac0;
    if (kt < 112)      { Ab = U;  astr = KU;  ac0 = kt * 32; }
    else if (kt < 128) { Ab = NF; astr = DIM; ac0 = kt * 32 - KU; }
    else               { Ab = G;  astr = KCP; ac0 = kt * 32 - (KU + DIM); }
    const int k0 = kt * 32;
#pragma unroll
    for (int t = 0; t < 2; ++t) {
      int idx = w * 128 + t * 64 + l;     // 16B granule id within A tile (linear dest)
      int row = idx >> 2, kp = idx & 3;
      int s = kp ^ ((row >> 1) & 3);
      int gm = m0 + row; gm = gm < M ? gm : M - 1;
      gload16(Ab + (size_t)gm * astr + ac0 + s * 8,
              (char*)sA[b] + (size_t)idx * 16);
    }
#pragma unroll
    for (int t = 0; t < 2; ++t) {
      int idx = w * 128 + t * 64 + l;
      int row = idx >> 2, kp = idx & 3;
      int s = kp ^ ((row >> 1) & 3);
      gload16(Bt + (size_t)(n0 + row) * KTOT + k0 + s * 8,
              (char*)sB[b] + (size_t)idx * 16);
    }
  };

  stage(0, 0);
  stage(1, 1);
  asm volatile("s_waitcnt vmcnt(4)" ::: "memory");
  __builtin_amdgcn_s_barrier();
  __builtin_amdgcn_sched_barrier(0);

  for (int kt = 0; kt < ktiles; ++kt) {
    const int cur = kt % 3;
    if (kt + 2 < ktiles) stage(kt + 2, (kt + 2) % 3);
    bf16x8 af[4], bfr[4];
#pragma unroll
    for (int i = 0; i < 4; ++i)
      af[i] = *(const bf16x8*)(sA[cur] + (size_t)(wr * 64 + i * 16 + lr) * 32 + sl * 8);
#pragma unroll
    for (int j = 0; j < 4; ++j)
      bfr[j] = *(const bf16x8*)(sB[cur] + (size_t)(wc * 64 + j * 16 + lr) * 32 + sl * 8);
#pragma unroll
    for (int i = 0; i < 4; ++i)
#pragma unroll
      for (int j = 0; j < 4; ++j)
        acc[i][j] = __builtin_amdgcn_mfma_f32_16x16x32_bf16(af[i], bfr[j], acc[i][j], 0, 0, 0);
    if (kt + 2 < ktiles) {
      asm volatile("s_waitcnt vmcnt(4)" ::: "memory");
    } else {
      asm volatile("s_waitcnt vmcnt(0)" ::: "memory");
    }
    __builtin_amdgcn_s_barrier();
    __builtin_amdgcn_sched_barrier(0);
  }
#pragma unroll
  for (int i = 0; i < 4; ++i) {
#pragma unroll
    for (int j = 0; j < 4; ++j) {
      int gj = n0 + wc * 64 + j * 16 + lr;
      float bias = b_lin[gj] + b_self[gj];
#pragma unroll
      for (int v = 0; v < 4; ++v) {
        int gm = m0 + wr * 64 + i * 16 + kg * 4 + v;
        if (gm < M)
          ((float*)Cout)[(size_t)gm * DIM + gj] = fmaxf(acc[i][j][v] + bias, 0.f);
      }
    }
  }
}

extern "C" void kernel_launch(void* const* d_in, const int* in_sizes, int n_in,
                              void* d_out, int out_size, void* d_ws, size_t ws_size,
                              hipStream_t stream) {
  const float* node_feat = (const float*)d_in[0];
  const float* edge_weight = (const float*)d_in[1];
  const float* edge_feat = (const float*)d_in[2];
  const float* W_lin = (const float*)d_in[3];
  const float* b_lin = (const float*)d_in[4];
  const float* W_self = (const float*)d_in[5];
  const float* b_self = (const float*)d_in[6];
  const float* W_edge = (const float*)d_in[7];
  const float* b_edge = (const float*)d_in[8];
  const int* node_in = (const int*)d_in[9];
  const int* node_out = (const int*)d_in[10];
  const int* relation = (const int*)d_in[11];
  float* out = (float*)d_out;

  const int N = in_sizes[0] / DIM;
  const int E = in_sizes[1];

  char* ws = (char*)d_ws;
  size_t off = 0;
  auto take = [&](size_t b) {
    char* p = ws + off;
    off += (b + 255) & ~(size_t)255;
    return p;
  };
  u16* NF       = (u16*)take((size_t)N * DIM * 2);
  u16* Bfull    = (u16*)take((size_t)DIM * KTOT * 2);
  u16* U        = (u16*)take((size_t)N * KU * 2);
  u16* G        = (u16*)take((size_t)N * KCP * 2);
  int* counts2  = (int*)take((size_t)N * 8 * 4);
  int* offs2    = (int*)take((size_t)N * 8 * 4);
  int* cursor2  = (int*)take((size_t)N * 8 * 4);
  int* totalCtr = (int*)take(256);
  uint4* quads  = (uint4*)take((size_t)E * 16);
  if (off > ws_size) return;  // workspace too small — fail visibly via absmax

  hipMemsetAsync(counts2, 0, (size_t)N * 8 * 4, stream);
  hipMemsetAsync(totalCtr, 0, 256, stream);

  {
    int total4 = N * DIM / 4;
    convA<<<(total4 + 255) / 256, 256, 0, stream>>>(node_feat, NF, total4);
  }
  {
    int total4 = DIM * 4096 / 4;
    buildBW<<<(total4 + 255) / 256, 256, 0, stream>>>(W_lin, W_self, Bfull, total4);
  }
  buildCx<<<KCP, 512, 0, stream>>>(W_edge, b_edge, W_lin, Bfull);

  countK2<<<(E + 255) / 256, 256, 0, stream>>>(node_out, relation, counts2, E);
  baseK<<<(N + 255) / 256, 256, 0, stream>>>(counts2, offs2, cursor2, totalCtr, N);
  fillK2<<<(E + 255) / 256, 256, 0, stream>>>(node_in, node_out, relation, edge_weight,
                                              cursor2, quads, E);

  // edge-G (HBM-compulsory ef gather) — independent of the NF gather
  gatherG2<<<N, 64, 0, stream>>>(edge_feat, quads, offs2, G);
  // node-path U: pass-partitioned L2-resident NF gather, group-per-node, no shfl
  {
    int nb = (N + 31) / 32;
    aggP<<<8 * nb, 256, 0, stream>>>(NF, quads, offs2, U, N, nb);
  }

  // single fused GEMM + bias + relu (A = [U | NF | G] region-split; 1-D swizzled grid)
  {
    int npan = (N + 127) / 128;
    gemm_br<<<npan * 4, 256, 0, stream>>>(U, NF, G, Bfull, b_lin, b_self, out, N);
  }
}

// Round 13
// 502.580 us; speedup vs baseline: 1.2802x; 1.2036x over previous
//
#include <hip/hip_runtime.h>
#include <stdint.h>

typedef unsigned short u16;
typedef __attribute__((ext_vector_type(8))) __bf16 bf16x8;
typedef __attribute__((ext_vector_type(8))) unsigned short u16x8;
typedef __attribute__((ext_vector_type(4))) float f32x4;

#define NREL 7
#define DIM  512
#define DEDGE 59
#define KC   420     // NREL*59 + NREL (weight-sum columns)
#define KCP  448     // padded to multiple of 32
#define KU   3584    // NREL*512 (node-path U region)
#define KTOT 4544    // KU + 512 (self, served from NF) + 448 (edge-G)

__device__ __forceinline__ float bf2f(u16 u) {
  union { unsigned u; float f; } c; c.u = ((unsigned)u) << 16; return c.f;
}
__device__ __forceinline__ u16 f2bf(float f) {
  union { float f; unsigned u; } c; c.f = f;
  unsigned r = ((c.u >> 16) & 1u) + 0x7FFFu;
  return (u16)((c.u + r) >> 16);
}

__device__ __forceinline__ void gload16(const void* g, void* l) {
  __builtin_amdgcn_global_load_lds(
      (__attribute__((address_space(1))) void*)g,
      (__attribute__((address_space(3))) void*)l, 16, 0, 0);
}

// ---- convert node_feat fp32 -> bf16 NF table [N,512] ----
__global__ void convA(const float* __restrict__ in, u16* __restrict__ out, int total4) {
  int i = blockIdx.x * 256 + threadIdx.x;
  if (i >= total4) return;
  float4 v = ((const float4*)in)[i];
  ushort4 r;
  r.x = f2bf(v.x); r.y = f2bf(v.y); r.z = f2bf(v.z); r.w = f2bf(v.w);
  ((ushort4*)out)[i] = r;
}

// ---- Bfull[o][k] bf16, [512][KTOT]: k<3584 -> W_lin[o][k]; 3584..4095 -> W_self[o][k-3584] ----
__global__ void buildBW(const float* __restrict__ W_lin, const float* __restrict__ W_self,
                        u16* __restrict__ Bfull, int total4) {
  int gid = blockIdx.x * 256 + threadIdx.x;
  if (gid >= total4) return;
  int idx = gid * 4;
  int o = idx >> 12;          // / 4096
  int k = idx & 4095;
  const float* src = (k < KU) ? (W_lin + (size_t)o * KU + k)
                              : (W_self + (size_t)o * DIM + (k - KU));
  float4 v = *(const float4*)src;
  ushort4 rr;
  rr.x = f2bf(v.x); rr.y = f2bf(v.y); rr.z = f2bf(v.z); rr.w = f2bf(v.w);
  *(ushort4*)(Bfull + (size_t)o * KTOT + k) = rr;
}

// ---- Bfull cols [4096, 4544): c=r*59+de -> sum_d W_edge[d,de]*W_lin[o,r*512+d];
//      c=413+r -> sum_d b_edge[d]*W_lin[o,r*512+d]; c>=420 -> 0 ----
__global__ __launch_bounds__(512) void buildCx(const float* __restrict__ W_edge,
                                               const float* __restrict__ b_edge,
                                               const float* __restrict__ W_lin,
                                               u16* __restrict__ Bfull) {
  int c = blockIdx.x;          // 0..447
  int o = threadIdx.x;         // 0..511
  u16* dst = Bfull + (size_t)o * KTOT + KU + DIM;  // col base 4096
  if (c >= KC) { dst[c] = 0; return; }
  __shared__ float col[DIM];
  int r;
  if (c < NREL * DEDGE) {
    r = c / DEDGE;
    int de = c - r * DEDGE;
    col[o] = W_edge[(size_t)o * DEDGE + de];
  } else {
    r = c - NREL * DEDGE;
    col[o] = b_edge[o];
  }
  __syncthreads();
  const float4* wv = (const float4*)(W_lin + (size_t)o * KU + (size_t)r * DIM);
  float acc = 0.f;
#pragma unroll 4
  for (int d4 = 0; d4 < DIM / 4; ++d4) {
    float4 wq = wv[d4];
    acc += col[d4 * 4 + 0] * wq.x + col[d4 * 4 + 1] * wq.y
         + col[d4 * 4 + 2] * wq.z + col[d4 * 4 + 3] * wq.w;
  }
  dst[c] = f2bf(acc);
}

// ---- two-level CSR keyed by (node_out, relation) ----
__global__ void countK2(const int* __restrict__ node_out, const int* __restrict__ relation,
                        int* __restrict__ counts2, int E) {
  int e = blockIdx.x * 256 + threadIdx.x;
  if (e < E) atomicAdd(&counts2[node_out[e] * 8 + relation[e]], 1);
}

// segment bases via atomic allocation — CSR segment ORDER is irrelevant (only
// disjointness matters), so no prefix scan needed.
__global__ void baseK(const int* __restrict__ counts2, int* __restrict__ offs2,
                      int* __restrict__ cursor2, int* __restrict__ totalCtr, int N) {
  int n = blockIdx.x * 256 + threadIdx.x;
  if (n >= N) return;
  int cnt[NREL];
  int s = 0;
#pragma unroll
  for (int r = 0; r < NREL; ++r) { cnt[r] = counts2[n * 8 + r]; s += cnt[r]; }
  int base = atomicAdd(totalCtr, s);
#pragma unroll
  for (int r = 0; r < NREL; ++r) {
    offs2[n * 8 + r] = base;
    cursor2[n * 8 + r] = base;
    base += cnt[r];
  }
  offs2[n * 8 + 7] = base;
}

// one 16B scattered store per edge: quad = (src, w_bits, e, 0)
__global__ void fillK2(const int* __restrict__ node_in, const int* __restrict__ node_out,
                       const int* __restrict__ relation, const float* __restrict__ ew,
                       int* __restrict__ cursor2, uint4* __restrict__ quads, int E) {
  int e = blockIdx.x * 256 + threadIdx.x;
  if (e >= E) return;
  int p = atomicAdd(&cursor2[node_out[e] * 8 + relation[e]], 1);
  quads[p] = make_uint4((unsigned)node_in[e], __float_as_uint(ew[e]), (unsigned)e, 0u);
}

// ---- MERGED aggregation kernel, grid-region co-scheduled:
//      blocks [0, ngg):   edge-G gather (4 nodes/block, one per wave) — ef reads are
//                         compulsory-HBM latency-bound; placed FIRST so they start early.
//      blocks [ngg, ngg+N): node-path U aggregation (R9-proven best: one node/block,
//                         4 waves relation-parallel {wid, wid+4}, 64 lanes x u16x8)
//                         — NF reads are L3-BW-bound (~3.3 TB/s measured).
//      The two phases use disjoint resources and overlap via co-residency. ----
__global__ __launch_bounds__(256) void aggBoth(const u16* __restrict__ NF,
                                               const float* __restrict__ ef,
                                               const uint4* __restrict__ quads,
                                               const int* __restrict__ offs2,
                                               u16* __restrict__ U,
                                               u16* __restrict__ G,
                                               int N, int ngg) {
  int bid = blockIdx.x;
  int wid = threadIdx.x >> 6, lane = threadIdx.x & 63;
  if (bid < ngg) {
    // ---- gatherG2 phase: node = bid*4 + wid ----
    int n = bid * 4 + wid;
    if (n >= N) return;
    u16* grow = G + (size_t)n * KCP;
    int base = n * 8;
    for (int r = 0; r < NREL; ++r) {
      int p0 = offs2[base + r], p1 = offs2[base + r + 1];
      float acc = 0.f;
      for (int p = p0; p < p1; ++p) {
        uint4 q = quads[p];
        int e = __builtin_amdgcn_readfirstlane((int)q.z);
        float w = __uint_as_float(__builtin_amdgcn_readfirstlane(q.y));
        float v = (lane < DEDGE) ? ef[(size_t)e * DEDGE + lane] : 1.0f;
        acc += w * v;
      }
      if (lane < DEDGE) grow[r * DEDGE + lane] = f2bf(acc);
      else if (lane == DEDGE) grow[NREL * DEDGE + r] = f2bf(acc);
    }
    if (lane >= 60) {
      for (int c = KC + (lane - 60); c < KCP; c += 4) grow[c] = 0;
    }
  } else {
    // ---- aggK phase (R9-proven): node = bid - ngg ----
    int n = bid - ngg;
    int o0 = lane * 8;
    u16* urow = U + (size_t)n * KU;
    int base = n * 8;
    for (int r = wid; r < NREL; r += 4) {
      int p0 = offs2[base + r], p1 = offs2[base + r + 1];
      float a[8];
#pragma unroll
      for (int j = 0; j < 8; ++j) a[j] = 0.f;
      for (int p = p0; p < p1; ++p) {
        uint4 q = quads[p];
        int src = __builtin_amdgcn_readfirstlane((int)q.x);
        float w = __uint_as_float(__builtin_amdgcn_readfirstlane(q.y));
        u16x8 hv = *(const u16x8*)(NF + (size_t)src * DIM + o0);
#pragma unroll
        for (int j = 0; j < 8; ++j) a[j] += w * bf2f(hv[j]);
      }
      u16x8 st;
#pragma unroll
      for (int j = 0; j < 8; ++j) st[j] = f2bf(a[j]);
      *(u16x8*)(urow + (size_t)r * DIM + o0) = st;
    }
  }
}

// ---- fused MFMA GEMM: out[M,512] = relu([U | NF | G] @ Bfull^T + b_lin + b_self)
//      A region-split: kt<112 -> U[M,3584]; 112..127 -> NF[M,512]; >=128 -> G[M,448].
//      R6 proven-best structure: T2 XOR bank-swizzle (conflicts=0), 3-buffer
//      counted-vmcnt pipeline, XCD panel-grouping swizzle, 128x128 block. ----
__global__ __launch_bounds__(256) void gemm_br(const u16* __restrict__ U,
                                               const u16* __restrict__ NF,
                                               const u16* __restrict__ G,
                                               const u16* __restrict__ Bt,
                                               const float* __restrict__ b_lin,
                                               const float* __restrict__ b_self,
                                               float* __restrict__ Cout, int M) {
  __shared__ __align__(16) u16 sA[3][128 * 32];
  __shared__ __align__(16) u16 sB[3][128 * 32];
  const int tid = threadIdx.x;
  const int w = tid >> 6, l = tid & 63;
  const int lr = l & 15, kg = l >> 4;
  const int sl = kg ^ ((lr >> 1) & 3);   // swizzled 16B-slot to read (lane-constant)

  const int id = blockIdx.x;
  const int npan = gridDim.x >> 2;
  const int nfull = (npan >> 3) << 3;
  int p, c;
  if (id < nfull * 4) {
    int g = id >> 5, r = id & 31;
    p = g * 8 + (r & 7);
    c = r >> 3;
  } else {
    int t = id - nfull * 4;
    p = nfull + (t >> 2);
    c = t & 3;
  }
  const int m0 = p * 128, n0 = c * 128;
  const int wr = w >> 1, wc = w & 1;
  f32x4 acc[4][4];
  const f32x4 z4 = {0.f, 0.f, 0.f, 0.f};
#pragma unroll
  for (int i = 0; i < 4; ++i)
#pragma unroll
    for (int j = 0; j < 4; ++j) acc[i][j] = z4;

  const int ktiles = KTOT / 32;   // 142

  auto stage = [&](int kt, int b) {
    const u16* Ab; int astr, ac0;
    if (kt < 112)      { Ab = U;  astr = KU;  ac0 = kt * 32; }
    else if (kt < 128) { Ab = NF; astr = DIM; ac0 = kt * 32 - KU; }
    else               { Ab = G;  astr = KCP; ac0 = kt * 32 - (KU + DIM); }
    const int k0 = kt * 32;
#pragma unroll
    for (int t = 0; t < 2; ++t) {
      int idx = w * 128 + t * 64 + l;     // 16B granule id within A tile (linear dest)
      int row = idx >> 2, kp = idx & 3;
      int s = kp ^ ((row >> 1) & 3);
      int gm = m0 + row; gm = gm < M ? gm : M - 1;
      gload16(Ab + (size_t)gm * astr + ac0 + s * 8,
              (char*)sA[b] + (size_t)idx * 16);
    }
#pragma unroll
    for (int t = 0; t < 2; ++t) {
      int idx = w * 128 + t * 64 + l;
      int row = idx >> 2, kp = idx & 3;
      int s = kp ^ ((row >> 1) & 3);
      gload16(Bt + (size_t)(n0 + row) * KTOT + k0 + s * 8,
              (char*)sB[b] + (size_t)idx * 16);
    }
  };

  stage(0, 0);
  stage(1, 1);
  asm volatile("s_waitcnt vmcnt(4)" ::: "memory");
  __builtin_amdgcn_s_barrier();
  __builtin_amdgcn_sched_barrier(0);

  for (int kt = 0; kt < ktiles; ++kt) {
    const int cur = kt % 3;
    if (kt + 2 < ktiles) stage(kt + 2, (kt + 2) % 3);
    bf16x8 af[4], bfr[4];
#pragma unroll
    for (int i = 0; i < 4; ++i)
      af[i] = *(const bf16x8*)(sA[cur] + (size_t)(wr * 64 + i * 16 + lr) * 32 + sl * 8);
#pragma unroll
    for (int j = 0; j < 4; ++j)
      bfr[j] = *(const bf16x8*)(sB[cur] + (size_t)(wc * 64 + j * 16 + lr) * 32 + sl * 8);
#pragma unroll
    for (int i = 0; i < 4; ++i)
#pragma unroll
      for (int j = 0; j < 4; ++j)
        acc[i][j] = __builtin_amdgcn_mfma_f32_16x16x32_bf16(af[i], bfr[j], acc[i][j], 0, 0, 0);
    if (kt + 2 < ktiles) {
      asm volatile("s_waitcnt vmcnt(4)" ::: "memory");
    } else {
      asm volatile("s_waitcnt vmcnt(0)" ::: "memory");
    }
    __builtin_amdgcn_s_barrier();
    __builtin_amdgcn_sched_barrier(0);
  }
#pragma unroll
  for (int i = 0; i < 4; ++i) {
#pragma unroll
    for (int j = 0; j < 4; ++j) {
      int gj = n0 + wc * 64 + j * 16 + lr;
      float bias = b_lin[gj] + b_self[gj];
#pragma unroll
      for (int v = 0; v < 4; ++v) {
        int gm = m0 + wr * 64 + i * 16 + kg * 4 + v;
        if (gm < M)
          ((float*)Cout)[(size_t)gm * DIM + gj] = fmaxf(acc[i][j][v] + bias, 0.f);
      }
    }
  }
}

extern "C" void kernel_launch(void* const* d_in, const int* in_sizes, int n_in,
                              void* d_out, int out_size, void* d_ws, size_t ws_size,
                              hipStream_t stream) {
  const float* node_feat = (const float*)d_in[0];
  const float* edge_weight = (const float*)d_in[1];
  const float* edge_feat = (const float*)d_in[2];
  const float* W_lin = (const float*)d_in[3];
  const float* b_lin = (const float*)d_in[4];
  const float* W_self = (const float*)d_in[5];
  const float* b_self = (const float*)d_in[6];
  const float* W_edge = (const float*)d_in[7];
  const float* b_edge = (const float*)d_in[8];
  const int* node_in = (const int*)d_in[9];
  const int* node_out = (const int*)d_in[10];
  const int* relation = (const int*)d_in[11];
  float* out = (float*)d_out;

  const int N = in_sizes[0] / DIM;
  const int E = in_sizes[1];

  char* ws = (char*)d_ws;
  size_t off = 0;
  auto take = [&](size_t b) {
    char* p = ws + off;
    off += (b + 255) & ~(size_t)255;
    return p;
  };
  u16* NF       = (u16*)take((size_t)N * DIM * 2);
  u16* Bfull    = (u16*)take((size_t)DIM * KTOT * 2);
  u16* U        = (u16*)take((size_t)N * KU * 2);
  u16* G        = (u16*)take((size_t)N * KCP * 2);
  int* counts2  = (int*)take((size_t)N * 8 * 4);
  int* offs2    = (int*)take((size_t)N * 8 * 4);
  int* cursor2  = (int*)take((size_t)N * 8 * 4);
  int* totalCtr = (int*)take(256);
  uint4* quads  = (uint4*)take((size_t)E * 16);
  if (off > ws_size) return;  // workspace too small — fail visibly via absmax

  hipMemsetAsync(counts2, 0, (size_t)N * 8 * 4, stream);
  hipMemsetAsync(totalCtr, 0, 256, stream);

  {
    int total4 = N * DIM / 4;
    convA<<<(total4 + 255) / 256, 256, 0, stream>>>(node_feat, NF, total4);
  }
  {
    int total4 = DIM * 4096 / 4;
    buildBW<<<(total4 + 255) / 256, 256, 0, stream>>>(W_lin, W_self, Bfull, total4);
  }
  buildCx<<<KCP, 512, 0, stream>>>(W_edge, b_edge, W_lin, Bfull);

  countK2<<<(E + 255) / 256, 256, 0, stream>>>(node_out, relation, counts2, E);
  baseK<<<(N + 255) / 256, 256, 0, stream>>>(counts2, offs2, cursor2, totalCtr, N);
  fillK2<<<(E + 255) / 256, 256, 0, stream>>>(node_in, node_out, relation, edge_weight,
                                              cursor2, quads, E);

  // merged edge-G (latency-bound, first) + node-path U (L3-BW-bound) — co-scheduled
  {
    int ngg = (N + 3) / 4;
    aggBoth<<<ngg + N, 256, 0, stream>>>(NF, edge_feat, quads, offs2, U, G, N, ngg);
  }

  // single fused GEMM + bias + relu (A = [U | NF | G] region-split; 1-D swizzled grid)
  {
    int npan = (N + 127) / 128;
    gemm_br<<<npan * 4, 256, 0, stream>>>(U, NF, G, Bfull, b_lin, b_self, out, N);
  }
}

// Round 14
// 475.425 us; speedup vs baseline: 1.3533x; 1.0571x over previous
//
#include <hip/hip_runtime.h>
#include <stdint.h>

typedef unsigned short u16;
typedef __attribute__((ext_vector_type(8))) __bf16 bf16x8;
typedef __attribute__((ext_vector_type(8))) unsigned short u16x8;
typedef __attribute__((ext_vector_type(4))) float f32x4;

#define NREL 7
#define DIM  512
#define DEDGE 59
#define KC   420     // NREL*59 + NREL (weight-sum columns)
#define KCP  448     // padded to multiple of 32
#define KU   3584    // NREL*512 (node-path U region)
#define KTOT 4544    // KU + 512 (self, served from NF) + 448 (edge-G)

__device__ __forceinline__ float bf2f(u16 u) {
  union { unsigned u; float f; } c; c.u = ((unsigned)u) << 16; return c.f;
}
__device__ __forceinline__ u16 f2bf(float f) {
  union { float f; unsigned u; } c; c.f = f;
  unsigned r = ((c.u >> 16) & 1u) + 0x7FFFu;
  return (u16)((c.u + r) >> 16);
}

__device__ __forceinline__ void gload16(const void* g, void* l) {
  __builtin_amdgcn_global_load_lds(
      (__attribute__((address_space(1))) void*)g,
      (__attribute__((address_space(3))) void*)l, 16, 0, 0);
}

// ---- convert node_feat fp32 -> bf16 NF table [N,512] ----
__global__ void convA(const float* __restrict__ in, u16* __restrict__ out, int total4) {
  int i = blockIdx.x * 256 + threadIdx.x;
  if (i >= total4) return;
  float4 v = ((const float4*)in)[i];
  ushort4 r;
  r.x = f2bf(v.x); r.y = f2bf(v.y); r.z = f2bf(v.z); r.w = f2bf(v.w);
  ((ushort4*)out)[i] = r;
}

// ---- Bfull[o][k] bf16, [512][KTOT]: k<3584 -> W_lin[o][k]; 3584..4095 -> W_self[o][k-3584] ----
__global__ void buildBW(const float* __restrict__ W_lin, const float* __restrict__ W_self,
                        u16* __restrict__ Bfull, int total4) {
  int gid = blockIdx.x * 256 + threadIdx.x;
  if (gid >= total4) return;
  int idx = gid * 4;
  int o = idx >> 12;          // / 4096
  int k = idx & 4095;
  const float* src = (k < KU) ? (W_lin + (size_t)o * KU + k)
                              : (W_self + (size_t)o * DIM + (k - KU));
  float4 v = *(const float4*)src;
  ushort4 rr;
  rr.x = f2bf(v.x); rr.y = f2bf(v.y); rr.z = f2bf(v.z); rr.w = f2bf(v.w);
  *(ushort4*)(Bfull + (size_t)o * KTOT + k) = rr;
}

// ---- Bfull cols [4096, 4544): c=r*59+de -> sum_d W_edge[d,de]*W_lin[o,r*512+d];
//      c=413+r -> sum_d b_edge[d]*W_lin[o,r*512+d]; c>=420 -> 0 ----
__global__ __launch_bounds__(512) void buildCx(const float* __restrict__ W_edge,
                                               const float* __restrict__ b_edge,
                                               const float* __restrict__ W_lin,
                                               u16* __restrict__ Bfull) {
  int c = blockIdx.x;          // 0..447
  int o = threadIdx.x;         // 0..511
  u16* dst = Bfull + (size_t)o * KTOT + KU + DIM;  // col base 4096
  if (c >= KC) { dst[c] = 0; return; }
  __shared__ float col[DIM];
  int r;
  if (c < NREL * DEDGE) {
    r = c / DEDGE;
    int de = c - r * DEDGE;
    col[o] = W_edge[(size_t)o * DEDGE + de];
  } else {
    r = c - NREL * DEDGE;
    col[o] = b_edge[o];
  }
  __syncthreads();
  const float4* wv = (const float4*)(W_lin + (size_t)o * KU + (size_t)r * DIM);
  float acc = 0.f;
#pragma unroll 4
  for (int d4 = 0; d4 < DIM / 4; ++d4) {
    float4 wq = wv[d4];
    acc += col[d4 * 4 + 0] * wq.x + col[d4 * 4 + 1] * wq.y
         + col[d4 * 4 + 2] * wq.z + col[d4 * 4 + 3] * wq.w;
  }
  dst[c] = f2bf(acc);
}

// ---- two-level CSR keyed by (node_out, relation) ----
__global__ void countK2(const int* __restrict__ node_out, const int* __restrict__ relation,
                        int* __restrict__ counts2, int E) {
  int e = blockIdx.x * 256 + threadIdx.x;
  if (e < E) atomicAdd(&counts2[node_out[e] * 8 + relation[e]], 1);
}

// segment bases via atomic allocation — CSR segment ORDER is irrelevant (only
// disjointness matters), so no prefix scan needed.
__global__ void baseK(const int* __restrict__ counts2, int* __restrict__ offs2,
                      int* __restrict__ cursor2, int* __restrict__ totalCtr, int N) {
  int n = blockIdx.x * 256 + threadIdx.x;
  if (n >= N) return;
  int cnt[NREL];
  int s = 0;
#pragma unroll
  for (int r = 0; r < NREL; ++r) { cnt[r] = counts2[n * 8 + r]; s += cnt[r]; }
  int base = atomicAdd(totalCtr, s);
#pragma unroll
  for (int r = 0; r < NREL; ++r) {
    offs2[n * 8 + r] = base;
    cursor2[n * 8 + r] = base;
    base += cnt[r];
  }
  offs2[n * 8 + 7] = base;
}

// one 16B scattered store per edge: quad = (src, w_bits, e, 0)
__global__ void fillK2(const int* __restrict__ node_in, const int* __restrict__ node_out,
                       const int* __restrict__ relation, const float* __restrict__ ew,
                       int* __restrict__ cursor2, uint4* __restrict__ quads, int E) {
  int e = blockIdx.x * 256 + threadIdx.x;
  if (e >= E) return;
  int p = atomicAdd(&cursor2[node_out[e] * 8 + relation[e]], 1);
  quads[p] = make_uint4((unsigned)node_in[e], __float_as_uint(ew[e]), (unsigned)e, 0u);
}

// ---- edge-G aggregation (rel-segmented, atomic-free): G[n][0..448) ----
//      ef reads are compulsory HBM (151 MB table, no reuse); 20K waves give the MLP.
__global__ __launch_bounds__(64) void gatherG2(const float* __restrict__ ef,
                                               const uint4* __restrict__ quads,
                                               const int* __restrict__ offs2,
                                               u16* __restrict__ G) {
  int n = blockIdx.x;
  int lane = threadIdx.x;
  u16* grow = G + (size_t)n * KCP;
  int base = n * 8;
  for (int r = 0; r < NREL; ++r) {
    int p0 = offs2[base + r], p1 = offs2[base + r + 1];
    float acc = 0.f;
    for (int p = p0; p < p1; ++p) {
      uint4 q = quads[p];
      int e = __builtin_amdgcn_readfirstlane((int)q.z);
      float w = __uint_as_float(__builtin_amdgcn_readfirstlane(q.y));
      float v = (lane < DEDGE) ? ef[(size_t)e * DEDGE + lane] : 1.0f;
      acc += w * v;
    }
    if (lane < DEDGE) grow[r * DEDGE + lane] = f2bf(acc);
    else if (lane == DEDGE) grow[NREL * DEDGE + r] = f2bf(acc);
  }
  if (lane >= 60) {
    for (int c = KC + (lane - 60); c < KCP; c += 4) grow[c] = 0;
  }
}

// ---- node-path aggregation (R9-proven best): one node/block, 4 waves
//      relation-parallel {wid, wid+4}; 64 lanes x u16x8 (full 1KB row per wave-read).
//      NF reads are L2/L3-BW-bound (~3.3 TB/s measured) — structural floor. ----
__global__ __launch_bounds__(256) void aggK(const u16* __restrict__ NF,
                                            const uint4* __restrict__ quads,
                                            const int* __restrict__ offs2,
                                            u16* __restrict__ U) {
  int n = blockIdx.x;
  int wid = threadIdx.x >> 6, lane = threadIdx.x & 63;
  int o0 = lane * 8;
  u16* urow = U + (size_t)n * KU;
  int base = n * 8;
  for (int r = wid; r < NREL; r += 4) {
    int p0 = offs2[base + r], p1 = offs2[base + r + 1];
    float a[8];
#pragma unroll
    for (int j = 0; j < 8; ++j) a[j] = 0.f;
    for (int p = p0; p < p1; ++p) {
      uint4 q = quads[p];
      int src = __builtin_amdgcn_readfirstlane((int)q.x);
      float w = __uint_as_float(__builtin_amdgcn_readfirstlane(q.y));
      u16x8 hv = *(const u16x8*)(NF + (size_t)src * DIM + o0);
#pragma unroll
      for (int j = 0; j < 8; ++j) a[j] += w * bf2f(hv[j]);
    }
    u16x8 st;
#pragma unroll
    for (int j = 0; j < 8; ++j) st[j] = f2bf(a[j]);
    *(u16x8*)(urow + (size_t)r * DIM + o0) = st;
  }
}

// ---- fused MFMA GEMM: out[M,512] = relu([U | NF | G] @ Bfull^T + b_lin + b_self)
//      A region-split: kt<112 -> U[M,3584]; 112..127 -> NF[M,512]; >=128 -> G[M,448].
//      R6 proven-best structure: T2 XOR bank-swizzle (conflicts=0), 3-buffer
//      counted-vmcnt pipeline, XCD panel-grouping swizzle, 128x128 block. ----
__global__ __launch_bounds__(256) void gemm_br(const u16* __restrict__ U,
                                               const u16* __restrict__ NF,
                                               const u16* __restrict__ G,
                                               const u16* __restrict__ Bt,
                                               const float* __restrict__ b_lin,
                                               const float* __restrict__ b_self,
                                               float* __restrict__ Cout, int M) {
  __shared__ __align__(16) u16 sA[3][128 * 32];
  __shared__ __align__(16) u16 sB[3][128 * 32];
  const int tid = threadIdx.x;
  const int w = tid >> 6, l = tid & 63;
  const int lr = l & 15, kg = l >> 4;
  const int sl = kg ^ ((lr >> 1) & 3);   // swizzled 16B-slot to read (lane-constant)

  const int id = blockIdx.x;
  const int npan = gridDim.x >> 2;
  const int nfull = (npan >> 3) << 3;
  int p, c;
  if (id < nfull * 4) {
    int g = id >> 5, r = id & 31;
    p = g * 8 + (r & 7);
    c = r >> 3;
  } else {
    int t = id - nfull * 4;
    p = nfull + (t >> 2);
    c = t & 3;
  }
  const int m0 = p * 128, n0 = c * 128;
  const int wr = w >> 1, wc = w & 1;
  f32x4 acc[4][4];
  const f32x4 z4 = {0.f, 0.f, 0.f, 0.f};
#pragma unroll
  for (int i = 0; i < 4; ++i)
#pragma unroll
    for (int j = 0; j < 4; ++j) acc[i][j] = z4;

  const int ktiles = KTOT / 32;   // 142

  auto stage = [&](int kt, int b) {
    const u16* Ab; int astr, ac0;
    if (kt < 112)      { Ab = U;  astr = KU;  ac0 = kt * 32; }
    else if (kt < 128) { Ab = NF; astr = DIM; ac0 = kt * 32 - KU; }
    else               { Ab = G;  astr = KCP; ac0 = kt * 32 - (KU + DIM); }
    const int k0 = kt * 32;
#pragma unroll
    for (int t = 0; t < 2; ++t) {
      int idx = w * 128 + t * 64 + l;     // 16B granule id within A tile (linear dest)
      int row = idx >> 2, kp = idx & 3;
      int s = kp ^ ((row >> 1) & 3);
      int gm = m0 + row; gm = gm < M ? gm : M - 1;
      gload16(Ab + (size_t)gm * astr + ac0 + s * 8,
              (char*)sA[b] + (size_t)idx * 16);
    }
#pragma unroll
    for (int t = 0; t < 2; ++t) {
      int idx = w * 128 + t * 64 + l;
      int row = idx >> 2, kp = idx & 3;
      int s = kp ^ ((row >> 1) & 3);
      gload16(Bt + (size_t)(n0 + row) * KTOT + k0 + s * 8,
              (char*)sB[b] + (size_t)idx * 16);
    }
  };

  stage(0, 0);
  stage(1, 1);
  asm volatile("s_waitcnt vmcnt(4)" ::: "memory");
  __builtin_amdgcn_s_barrier();
  __builtin_amdgcn_sched_barrier(0);

  for (int kt = 0; kt < ktiles; ++kt) {
    const int cur = kt % 3;
    if (kt + 2 < ktiles) stage(kt + 2, (kt + 2) % 3);
    bf16x8 af[4], bfr[4];
#pragma unroll
    for (int i = 0; i < 4; ++i)
      af[i] = *(const bf16x8*)(sA[cur] + (size_t)(wr * 64 + i * 16 + lr) * 32 + sl * 8);
#pragma unroll
    for (int j = 0; j < 4; ++j)
      bfr[j] = *(const bf16x8*)(sB[cur] + (size_t)(wc * 64 + j * 16 + lr) * 32 + sl * 8);
#pragma unroll
    for (int i = 0; i < 4; ++i)
#pragma unroll
      for (int j = 0; j < 4; ++j)
        acc[i][j] = __builtin_amdgcn_mfma_f32_16x16x32_bf16(af[i], bfr[j], acc[i][j], 0, 0, 0);
    if (kt + 2 < ktiles) {
      asm volatile("s_waitcnt vmcnt(4)" ::: "memory");
    } else {
      asm volatile("s_waitcnt vmcnt(0)" ::: "memory");
    }
    __builtin_amdgcn_s_barrier();
    __builtin_amdgcn_sched_barrier(0);
  }
#pragma unroll
  for (int i = 0; i < 4; ++i) {
#pragma unroll
    for (int j = 0; j < 4; ++j) {
      int gj = n0 + wc * 64 + j * 16 + lr;
      float bias = b_lin[gj] + b_self[gj];
#pragma unroll
      for (int v = 0; v < 4; ++v) {
        int gm = m0 + wr * 64 + i * 16 + kg * 4 + v;
        if (gm < M)
          ((float*)Cout)[(size_t)gm * DIM + gj] = fmaxf(acc[i][j][v] + bias, 0.f);
      }
    }
  }
}

extern "C" void kernel_launch(void* const* d_in, const int* in_sizes, int n_in,
                              void* d_out, int out_size, void* d_ws, size_t ws_size,
                              hipStream_t stream) {
  const float* node_feat = (const float*)d_in[0];
  const float* edge_weight = (const float*)d_in[1];
  const float* edge_feat = (const float*)d_in[2];
  const float* W_lin = (const float*)d_in[3];
  const float* b_lin = (const float*)d_in[4];
  const float* W_self = (const float*)d_in[5];
  const float* b_self = (const float*)d_in[6];
  const float* W_edge = (const float*)d_in[7];
  const float* b_edge = (const float*)d_in[8];
  const int* node_in = (const int*)d_in[9];
  const int* node_out = (const int*)d_in[10];
  const int* relation = (const int*)d_in[11];
  float* out = (float*)d_out;

  const int N = in_sizes[0] / DIM;
  const int E = in_sizes[1];

  char* ws = (char*)d_ws;
  size_t off = 0;
  auto take = [&](size_t b) {
    char* p = ws + off;
    off += (b + 255) & ~(size_t)255;
    return p;
  };
  u16* NF       = (u16*)take((size_t)N * DIM * 2);
  u16* Bfull    = (u16*)take((size_t)DIM * KTOT * 2);
  u16* U        = (u16*)take((size_t)N * KU * 2);
  u16* G        = (u16*)take((size_t)N * KCP * 2);
  int* counts2  = (int*)take((size_t)N * 8 * 4);
  int* offs2    = (int*)take((size_t)N * 8 * 4);
  int* cursor2  = (int*)take((size_t)N * 8 * 4);
  int* totalCtr = (int*)take(256);
  uint4* quads  = (uint4*)take((size_t)E * 16);
  if (off > ws_size) return;  // workspace too small — fail visibly via absmax

  hipMemsetAsync(counts2, 0, (size_t)N * 8 * 4, stream);
  hipMemsetAsync(totalCtr, 0, 256, stream);

  {
    int total4 = N * DIM / 4;
    convA<<<(total4 + 255) / 256, 256, 0, stream>>>(node_feat, NF, total4);
  }
  {
    int total4 = DIM * 4096 / 4;
    buildBW<<<(total4 + 255) / 256, 256, 0, stream>>>(W_lin, W_self, Bfull, total4);
  }
  buildCx<<<KCP, 512, 0, stream>>>(W_edge, b_edge, W_lin, Bfull);

  countK2<<<(E + 255) / 256, 256, 0, stream>>>(node_out, relation, counts2, E);
  baseK<<<(N + 255) / 256, 256, 0, stream>>>(counts2, offs2, cursor2, totalCtr, N);
  fillK2<<<(E + 255) / 256, 256, 0, stream>>>(node_in, node_out, relation, edge_weight,
                                              cursor2, quads, E);

  // edge-G (HBM-compulsory ef gather), then node-path U (L3-BW-bound) — separate,
  // serial: measured best (merging/fusing/partitioning all regressed, R10-R13)
  gatherG2<<<N, 64, 0, stream>>>(edge_feat, quads, offs2, G);
  aggK<<<N, 256, 0, stream>>>(NF, quads, offs2, U);

  // single fused GEMM + bias + relu (A = [U | NF | G] region-split; 1-D swizzled grid)
  {
    int npan = (N + 127) / 128;
    gemm_br<<<npan * 4, 256, 0, stream>>>(U, NF, G, Bfull, b_lin, b_self, out, N);
  }
}